// Round 11
// baseline (41.388 us; speedup 1.0000x reference)
//
#include <hip/hip_runtime.h>

// ParallelLatticeModel v11 — DIAGNOSTIC ROUND: v8 (best, 14.13 us) with the
// post-staging body repeated 8x (idempotent stores, LICM blocked by asm
// touches). Purpose: (a) surface the kernel in rocprof top-5 (sorted by
// dur_us; 40us poison fills have hidden every variant since R2), exposing
// VALUBusy/Occupancy/VGPR_Count/LDS conflicts for the real body; (b)
// decompose dur = k_body + c_fixed:  14.13 = k + c,  diag = 8k + c.
//   diag ~ 85-100us -> body-bound (k~11), counters point the next fix.
//   diag ~ 45-60us  -> fixed overhead c ~ 8-10us dominates; body near roofline.
//
// Everything else is byte-identical to v8 (test-verified layouts).

typedef _Float16 f16x4 __attribute__((ext_vector_type(4)));
typedef float f32x4 __attribute__((ext_vector_type(4)));
typedef float f32x2 __attribute__((ext_vector_type(2)));

namespace {
constexpr int kD = 16, kE = 24, kK = 16, kNV = 16;
constexpr int kThreads = 256;
constexpr int kRPB = 64;             // rows per block
constexpr int kRep = 8;              // DIAGNOSTIC repeat factor
constexpr int kKpS  = 17;            // sKp row stride (floats)  - odd pad
constexpr int kAffS = 17;            // sAff row stride (f32x2)  - odd pad
constexpr int kWS   = 67;            // sW region stride (f16x4) - odd pad
constexpr int kK2S  = 20;            // sK2 row stride (floats)  - 16B aligned
}

static __device__ __forceinline__ f32x2 fma2(f32x2 a, f32x2 b, f32x2 c) {
#if __has_builtin(__builtin_elementwise_fma)
    return __builtin_elementwise_fma(a, b, c);
#else
    return (f32x2){fmaf(a[0], b[0], c[0]), fmaf(a[1], b[1], c[1])};
#endif
}
static __device__ __forceinline__ f32x2 fma2s(f32x2 a, float b, float c) {
    return fma2(a, (f32x2){b, b}, (f32x2){c, c});
}
static __device__ __forceinline__ f32x2 clamp01(f32x2 v) {
    return (f32x2){fminf(fmaxf(v[0], 0.f), 1.f), fminf(fmaxf(v[1], 0.f), 1.f)};
}

__global__ __launch_bounds__(kThreads, 8) void lattice_fwd(
    const float* __restrict__ x,
    const float* __restrict__ cal_kp,    // [D][K]
    const float* __restrict__ cal_vals,  // [D][K]
    const float* __restrict__ k1,        // [E][4][16]
    const float* __restrict__ k2,        // [E][16]
    float* __restrict__ out)             // [B][E]
{
    __shared__ float sKp[kD * kKpS];     // padded kp rows, +INF sentinel 1.1KB
    __shared__ f32x2 sAff[kD * kAffS];   // {slope, intercept} padded     2.1KB
    __shared__ f16x4 sW[16 * kWS];       // [mtile*lattice padded][lane]  8.4KB
    __shared__ f16x4 sK1[4 * 2 * 64];    // [lattice][ntile][lane]        4 KB
    __shared__ float sK2[32 * kK2S];     // [e][j4]{A,B,dA,dB}            2.5KB

    const int tid  = threadIdx.x;
    const int lane = tid & 63;
    const int wv   = __builtin_amdgcn_readfirstlane(tid >> 6);   // 0..3
    const int q    = lane >> 4;          // feature-quarter / lattice
    const int r15  = lane & 15;          // row in tile (ph1) / col e (ph2)

    const int rowBase = blockIdx.x * kRPB + wv * 16;

    // coalesced x prefetch: wave covers rows rowBase..+15 (1KB contiguous)
    f32x4 xin = *reinterpret_cast<const f32x4*>(
        x + (size_t)(rowBase + r15) * kD + 4 * q);

    // ---------------- phase 0: stage tables ----------------
    {   // kp search rows (padded): +INF sentinel at k=15
        int d = tid >> 4, k = tid & 15;
        sKp[d * kKpS + k] = (k == 15) ? __builtin_inff() : cal_kp[tid];
    }
    if (tid < kD * 15) {   // affine entries {slope, intercept}
        int d = tid / 15;
        int k = tid - d * 15;
        float kp0 = cal_kp[d * kK + k];
        float kp1 = cal_kp[d * kK + k + 1];
        float v0  = cal_vals[d * kK + k];
        float v1  = cal_vals[d * kK + k + 1];
        float dxv = kp1 - kp0;
        float slope = (dxv > 0.0f) ? (v1 - v0) / dxv : 0.0f;
        sAff[d * kAffS + k] = (f32x2){slope, fmaf(-slope, kp0, v0)};
    }
    // k1 B-frags: lane ls holds B[k=4*(ls>>4)+j][col=16n+(ls&15)]
    #pragma unroll
    for (int s0 = 0; s0 < 2; ++s0) {
        int s  = tid + s0 * kThreads;    // 0..511
        int l  = s >> 7;
        int n  = (s >> 6) & 1;
        int ls = s & 63;
        int e  = n * 16 + (ls & 15);
        int g  = ls >> 4;
        f16x4 v = {(_Float16)0.f, (_Float16)0.f, (_Float16)0.f, (_Float16)0.f};
        if (e < kE) {
            const float* src = k1 + ((size_t)(e * 4 + l) * kNV + 4 * g);
            v[0] = (_Float16)src[0]; v[1] = (_Float16)src[1];
            v[2] = (_Float16)src[2]; v[3] = (_Float16)src[3];
        }
        sK1[s] = v;
    }
    {   // k2 per-(e,j4) packs {A,B,dA,dB}
        int e = tid >> 3, j4 = (tid >> 1) & 3, h = tid & 1;
        float a = 0.f, d = 0.f;
        if (e < kE) {
            a = k2[e * kNV + 4 * j4 + 2 * h];
            d = k2[e * kNV + 4 * j4 + 2 * h + 1] - a;
        }
        sK2[e * kK2S + 4 * j4 + h]     = a;
        sK2[e * kK2S + 4 * j4 + 2 + h] = d;
    }

    __syncthreads();   // the ONLY block-wide barrier

    // ============ DIAGNOSTIC: repeat the body kRep times ============
    #pragma unroll 1
    for (int rep = 0; rep < kRep; ++rep) {
        f32x4 xcur = xin;
        // block LICM across reps: make xcur opaque (zero-cost)
        asm volatile("" : "+v"(xcur[0]), "+v"(xcur[1]), "+v"(xcur[2]), "+v"(xcur[3]));

        // ------- phase 1: calibrate features 4q..4q+3 of row r15 -------
        float xc[4];
        #pragma unroll
        for (int i = 0; i < 4; ++i) {
            const int d = 4 * q + i;
            const float xv = xcur[i];
            const float* kpb = &sKp[d * kKpS];
            int j = 0;
            #pragma unroll
            for (int s = 8; s >= 1; s >>= 1) {    // 4x: b32 read + cmp + cndmask
                float kps = kpb[j + s];
                j = (xv >= kps) ? j + s : j;
            }
            f32x2 ent = sAff[d * kAffS + j];      // {slope, intercept}
            xc[i] = fminf(fmaxf(fmaf(ent[0], xv, ent[1]), 0.0f), 1.0f);
        }

        // multilinear corner weights for lattice q (dim0 = MSB)
        float wf[16];
        {
            float a = xc[0], b = xc[1], c = xc[2], d = xc[3];
            float t2[2] = {1.0f - a, a};
            float t4[4];
            #pragma unroll
            for (int j = 0; j < 2; ++j) { t4[2*j] = t2[j]*(1.0f-b); t4[2*j+1] = t2[j]*b; }
            float t8[8];
            #pragma unroll
            for (int j = 0; j < 4; ++j) { t8[2*j] = t4[j]*(1.0f-c); t8[2*j+1] = t4[j]*c; }
            #pragma unroll
            for (int j = 0; j < 8; ++j) { wf[2*j] = t8[j]*(1.0f-d); wf[2*j+1] = t8[j]*d; }
        }

        // A-frags into the wave's OWN padded M-tile region (wave-private)
        #pragma unroll
        for (int g = 0; g < 4; ++g) {
            f16x4 v;
            v[0] = (_Float16)wf[4*g+0]; v[1] = (_Float16)wf[4*g+1];
            v[2] = (_Float16)wf[4*g+2]; v[3] = (_Float16)wf[4*g+3];
            sW[(wv * 4 + q) * kWS + r15 + 16 * g] = v;
        }
        asm volatile("s_waitcnt lgkmcnt(0)" ::: "memory");   // wave-local fence

        f16x4 af[4];
        #pragma unroll
        for (int l = 0; l < 4; ++l) af[l] = sW[(wv * 4 + l) * kWS + lane];

        // ---------------- phase 2: MFMA layer-1 + packed layer-2 ----------------
        #pragma unroll
        for (int n = 0; n < 2; ++n) {
            const int e = n * 16 + r15;

            f32x4 acc[4];
            #pragma unroll
            for (int l = 0; l < 4; ++l) {
                f16x4 bf = sK1[(l * 2 + n) * 64 + lane];
                acc[l] = __builtin_amdgcn_mfma_f32_16x16x16f16(
                    af[l], bf, (f32x4){0.f, 0.f, 0.f, 0.f}, 0, 0, 0);
            }

            f32x2 h3a = clamp01((f32x2){acc[3][0], acc[3][1]});
            f32x2 h3b = clamp01((f32x2){acc[3][2], acc[3][3]});
            f32x2 h2a = clamp01((f32x2){acc[2][0], acc[2][1]});
            f32x2 h2b = clamp01((f32x2){acc[2][2], acc[2][3]});

            f32x2 v4a[4], v4b[4];
            const float* kr = &sK2[e * kK2S];
            #pragma unroll
            for (int j4 = 0; j4 < 4; ++j4) {
                f32x4 kq = *reinterpret_cast<const f32x4*>(kr + 4 * j4); // {A,B,dA,dB}
                f32x2 a0 = fma2s(h3a, kq[2], kq[0]);
                f32x2 b0 = fma2s(h3a, kq[3], kq[1]);
                v4a[j4]  = fma2(h2a, b0 - a0, a0);
                f32x2 a1 = fma2s(h3b, kq[2], kq[0]);
                f32x2 b1 = fma2s(h3b, kq[3], kq[1]);
                v4b[j4]  = fma2(h2b, b1 - a1, a1);
            }

            #pragma unroll
            for (int p = 0; p < 2; ++p) {
                f32x2 h1 = clamp01((f32x2){acc[1][2*p], acc[1][2*p+1]});
                f32x2 h0 = clamp01((f32x2){acc[0][2*p], acc[0][2*p+1]});
                const f32x2* v4 = (p == 0) ? v4a : v4b;   // compile-time select
                f32x2 w0 = fma2(h1, v4[1] - v4[0], v4[0]);
                f32x2 w1 = fma2(h1, v4[3] - v4[2], v4[2]);
                f32x2 o  = fma2(h0, w1 - w0, w0);
                if (e < kE) {   // exec-masked store (row=4q+2p(+1), col=e)
                    size_t r0 = (size_t)(rowBase + q * 4 + 2 * p);
                    out[r0 * kE + e]       = o[0];
                    out[(r0 + 1) * kE + e] = o[1];
                }
            }
        }
    }
}

extern "C" void kernel_launch(void* const* d_in, const int* in_sizes, int n_in,
                              void* d_out, int out_size, void* d_ws, size_t ws_size,
                              hipStream_t stream) {
    const float* x        = (const float*)d_in[0];
    const float* cal_kp   = (const float*)d_in[1];
    const float* cal_vals = (const float*)d_in[2];
    const float* k1       = (const float*)d_in[3];
    const float* k2       = (const float*)d_in[4];
    float* out = (float*)d_out;

    hipLaunchKernelGGL(lattice_fwd, dim3(131072 / kRPB), dim3(kThreads), 0, stream,
                       x, cal_kp, cal_vals, k1, k2, out);
}

// Round 12
// 12.953 us; speedup vs baseline: 3.1952x; 3.1952x over previous
//
#include <hip/hip_runtime.h>

// ParallelLatticeModel v12: amortize the per-block prologue (R11 diagnostic:
// body ~3.9us, non-body ~10.2us). Block = 1024 threads = 16 waves, each wave
// one 16-row M-tile -> 256 rows/block, 512 blocks (4x fewer stagings, 4x
// fewer WG ramps, staging parallelized over 4x threads). Body per wave is
// byte-identical to v8 (test-verified layouts v3-v11).
//
// B=131072 rows, D=16 features, 4 lattices x 4 dims (16 corners), E=24 cols,
// K=16 calibration keypoints.
//
// Per wave: lane = r15 + 16q calibrates features 4q..4q+3 of row r15 (binary
// search in padded sKp + affine sAff entry), builds lattice-q corner weights,
// exchanges fp16 A-frags through the wave's padded sW region (lgkmcnt fence,
// single block barrier total), then 4 lattices x 2 N-tiles of
// v_mfma_f32_16x16x16_f16 and the packed layer-2 lerp chain.
// C layout: col=lane&15, row=4*(lane>>4)+reg.

typedef _Float16 f16x4 __attribute__((ext_vector_type(4)));
typedef float f32x4 __attribute__((ext_vector_type(4)));
typedef float f32x2 __attribute__((ext_vector_type(2)));

namespace {
constexpr int kD = 16, kE = 24, kK = 16, kNV = 16;
constexpr int kThreads = 1024;       // 16 waves
constexpr int kWaves = 16;
constexpr int kRPB = 256;            // rows per block (16 waves x 16 rows)
constexpr int kKpS  = 17;            // sKp row stride (floats)  - odd pad
constexpr int kAffS = 17;            // sAff row stride (f32x2)  - odd pad
constexpr int kWS   = 67;            // sW region stride (f16x4) - odd pad
constexpr int kK2S  = 20;            // sK2 row stride (floats)  - 16B aligned
}

static __device__ __forceinline__ f32x2 fma2(f32x2 a, f32x2 b, f32x2 c) {
#if __has_builtin(__builtin_elementwise_fma)
    return __builtin_elementwise_fma(a, b, c);
#else
    return (f32x2){fmaf(a[0], b[0], c[0]), fmaf(a[1], b[1], c[1])};
#endif
}
static __device__ __forceinline__ f32x2 fma2s(f32x2 a, float b, float c) {
    return fma2(a, (f32x2){b, b}, (f32x2){c, c});
}
static __device__ __forceinline__ f32x2 clamp01(f32x2 v) {
    return (f32x2){fminf(fmaxf(v[0], 0.f), 1.f), fminf(fmaxf(v[1], 0.f), 1.f)};
}

__global__ __launch_bounds__(kThreads, 8) void lattice_fwd(
    const float* __restrict__ x,
    const float* __restrict__ cal_kp,    // [D][K]
    const float* __restrict__ cal_vals,  // [D][K]
    const float* __restrict__ k1,        // [E][4][16]
    const float* __restrict__ k2,        // [E][16]
    float* __restrict__ out)             // [B][E]
{
    __shared__ float sKp[kD * kKpS];         // padded kp rows, +INF      1.1KB
    __shared__ f32x2 sAff[kD * kAffS];       // {slope, intercept} padded 2.1KB
    __shared__ f16x4 sW[kWaves * 4 * kWS];   // [wave*lattice pad][lane] 33.5KB
    __shared__ f16x4 sK1[4 * 2 * 64];        // [lattice][ntile][lane]    4 KB
    __shared__ float sK2[32 * kK2S];         // [e][j4]{A,B,dA,dB}        2.5KB

    const int tid  = threadIdx.x;
    const int lane = tid & 63;
    const int wv   = __builtin_amdgcn_readfirstlane(tid >> 6);   // 0..15
    const int q    = lane >> 4;          // feature-quarter / lattice
    const int r15  = lane & 15;          // row in tile (ph1) / col e (ph2)

    const int rowBase = blockIdx.x * kRPB + wv * 16;

    // coalesced x prefetch: wave covers rows rowBase..+15 (1KB contiguous)
    f32x4 xin = *reinterpret_cast<const f32x4*>(
        x + (size_t)(rowBase + r15) * kD + 4 * q);

    // ---------------- phase 0: stage tables (1024 threads, one shot) -------
    if (tid < kD * 16) {   // kp search rows (padded): +INF sentinel at k=15
        int d = tid >> 4, k = tid & 15;
        sKp[d * kKpS + k] = (k == 15) ? __builtin_inff() : cal_kp[tid];
    }
    if (tid < kD * 15) {   // affine entries {slope, intercept}
        int d = tid / 15;
        int k = tid - d * 15;
        float kp0 = cal_kp[d * kK + k];
        float kp1 = cal_kp[d * kK + k + 1];
        float v0  = cal_vals[d * kK + k];
        float v1  = cal_vals[d * kK + k + 1];
        float dxv = kp1 - kp0;
        float slope = (dxv > 0.0f) ? (v1 - v0) / dxv : 0.0f;
        sAff[d * kAffS + k] = (f32x2){slope, fmaf(-slope, kp0, v0)};
    }
    if (tid < 512) {   // k1 B-frags: lane ls holds B[k=4*(ls>>4)+j][col=16n+(ls&15)]
        int s  = tid;
        int l  = s >> 7;
        int n  = (s >> 6) & 1;
        int ls = s & 63;
        int e  = n * 16 + (ls & 15);
        int g  = ls >> 4;
        f16x4 v = {(_Float16)0.f, (_Float16)0.f, (_Float16)0.f, (_Float16)0.f};
        if (e < kE) {
            const float* src = k1 + ((size_t)(e * 4 + l) * kNV + 4 * g);
            v[0] = (_Float16)src[0]; v[1] = (_Float16)src[1];
            v[2] = (_Float16)src[2]; v[3] = (_Float16)src[3];
        }
        sK1[s] = v;
    }
    if (tid < 256) {   // k2 per-(e,j4) packs {A,B,dA,dB}
        int e = tid >> 3, j4 = (tid >> 1) & 3, h = tid & 1;
        float a = 0.f, d = 0.f;
        if (e < kE) {
            a = k2[e * kNV + 4 * j4 + 2 * h];
            d = k2[e * kNV + 4 * j4 + 2 * h + 1] - a;
        }
        sK2[e * kK2S + 4 * j4 + h]     = a;
        sK2[e * kK2S + 4 * j4 + 2 + h] = d;
    }

    __syncthreads();   // the ONLY block-wide barrier

    // ------------- phase 1: calibrate features 4q..4q+3 of row r15 -------------
    float xc[4];
    #pragma unroll
    for (int i = 0; i < 4; ++i) {
        const int d = 4 * q + i;
        const float xv = xin[i];
        const float* kpb = &sKp[d * kKpS];
        int j = 0;
        #pragma unroll
        for (int s = 8; s >= 1; s >>= 1) {        // 4x: b32 read + cmp + cndmask
            float kps = kpb[j + s];
            j = (xv >= kps) ? j + s : j;
        }
        f32x2 ent = sAff[d * kAffS + j];          // {slope, intercept}
        xc[i] = fminf(fmaxf(fmaf(ent[0], xv, ent[1]), 0.0f), 1.0f);
    }

    // multilinear corner weights for lattice q (dim0 = MSB of corner index)
    float wf[16];
    {
        float a = xc[0], b = xc[1], c = xc[2], d = xc[3];
        float t2[2] = {1.0f - a, a};
        float t4[4];
        #pragma unroll
        for (int j = 0; j < 2; ++j) { t4[2*j] = t2[j]*(1.0f-b); t4[2*j+1] = t2[j]*b; }
        float t8[8];
        #pragma unroll
        for (int j = 0; j < 4; ++j) { t8[2*j] = t4[j]*(1.0f-c); t8[2*j+1] = t4[j]*c; }
        #pragma unroll
        for (int j = 0; j < 8; ++j) { wf[2*j] = t8[j]*(1.0f-d); wf[2*j+1] = t8[j]*d; }
    }

    // A-frags into the wave's OWN padded region (wave-private)
    #pragma unroll
    for (int g = 0; g < 4; ++g) {
        f16x4 v;
        v[0] = (_Float16)wf[4*g+0]; v[1] = (_Float16)wf[4*g+1];
        v[2] = (_Float16)wf[4*g+2]; v[3] = (_Float16)wf[4*g+3];
        sW[(wv * 4 + q) * kWS + r15 + 16 * g] = v;
    }
    asm volatile("s_waitcnt lgkmcnt(0)" ::: "memory");   // wave-local fence

    f16x4 af[4];
    #pragma unroll
    for (int l = 0; l < 4; ++l) af[l] = sW[(wv * 4 + l) * kWS + lane];

    // ---------------- phase 2: MFMA layer-1 + packed layer-2 ----------------
    #pragma unroll
    for (int n = 0; n < 2; ++n) {
        const int e = n * 16 + r15;

        f32x4 acc[4];
        #pragma unroll
        for (int l = 0; l < 4; ++l) {
            f16x4 bf = sK1[(l * 2 + n) * 64 + lane];
            acc[l] = __builtin_amdgcn_mfma_f32_16x16x16f16(
                af[l], bf, (f32x4){0.f, 0.f, 0.f, 0.f}, 0, 0, 0);
        }

        // h3/h2 for both row-pairs (p=0: rows 4q+0,1; p=1: rows 4q+2,3)
        f32x2 h3a = clamp01((f32x2){acc[3][0], acc[3][1]});
        f32x2 h3b = clamp01((f32x2){acc[3][2], acc[3][3]});
        f32x2 h2a = clamp01((f32x2){acc[2][0], acc[2][1]});
        f32x2 h2b = clamp01((f32x2){acc[2][2], acc[2][3]});

        f32x2 v4a[4], v4b[4];
        const float* kr = &sK2[e * kK2S];
        #pragma unroll
        for (int j4 = 0; j4 < 4; ++j4) {
            f32x4 kq = *reinterpret_cast<const f32x4*>(kr + 4 * j4); // {A,B,dA,dB}
            f32x2 a0 = fma2s(h3a, kq[2], kq[0]);
            f32x2 b0 = fma2s(h3a, kq[3], kq[1]);
            v4a[j4]  = fma2(h2a, b0 - a0, a0);
            f32x2 a1 = fma2s(h3b, kq[2], kq[0]);
            f32x2 b1 = fma2s(h3b, kq[3], kq[1]);
            v4b[j4]  = fma2(h2b, b1 - a1, a1);
        }

        #pragma unroll
        for (int p = 0; p < 2; ++p) {
            f32x2 h1 = clamp01((f32x2){acc[1][2*p], acc[1][2*p+1]});
            f32x2 h0 = clamp01((f32x2){acc[0][2*p], acc[0][2*p+1]});
            const f32x2* v4 = (p == 0) ? v4a : v4b;   // compile-time select
            f32x2 w0 = fma2(h1, v4[1] - v4[0], v4[0]);
            f32x2 w1 = fma2(h1, v4[3] - v4[2], v4[2]);
            f32x2 o  = fma2(h0, w1 - w0, w0);
            if (e < kE) {   // exec-masked store (C layout: row=4q+2p(+1), col=e)
                size_t r0 = (size_t)(rowBase + q * 4 + 2 * p);
                out[r0 * kE + e]       = o[0];
                out[(r0 + 1) * kE + e] = o[1];
            }
        }
    }
}

extern "C" void kernel_launch(void* const* d_in, const int* in_sizes, int n_in,
                              void* d_out, int out_size, void* d_ws, size_t ws_size,
                              hipStream_t stream) {
    const float* x        = (const float*)d_in[0];
    const float* cal_kp   = (const float*)d_in[1];
    const float* cal_vals = (const float*)d_in[2];
    const float* k1       = (const float*)d_in[3];
    const float* k2       = (const float*)d_in[4];
    float* out = (float*)d_out;

    hipLaunchKernelGGL(lattice_fwd, dim3(131072 / kRPB), dim3(kThreads), 0, stream,
                       x, cal_kp, cal_vals, k1, k2, out);
}